// Round 2
// baseline (898.779 us; speedup 1.0000x reference)
//
#include <hip/hip_runtime.h>
#include <hip/hip_bf16.h>

// LFA_self: fused (proj -> MHA over 49 tokens -> proj) for MI355X.
// Algebra: scores = Xq (Wq Wk^T) Xk^T (contract over head's 1024 floats);
// out = (attn . Xv) (Wv Wo) + bv Wo + bo. Head h = contiguous 1024-float
// slice per token. One block per (b,h): 512 blocks, 512 threads (8 waves),
// 2 blocks/CU -> 16 waves/CU.

#define NT 49            // tokens
#define TOKS 16384       // floats per (b,t)
#define HSL 1024         // floats per head slice
#define BIGS 132         // big[] row stride (floats)

typedef __attribute__((ext_vector_type(8))) short bf16x8;
typedef __attribute__((ext_vector_type(4))) float f32x4;

__device__ __forceinline__ ushort f2bf(float f) {
    union { float f; unsigned u; } v; v.f = f;
    return (ushort)((v.u + 0x7fffu + ((v.u >> 16) & 1u)) >> 16);   // RNE
}

__global__ __launch_bounds__(512, 4) void lfa_fused(
    const float* __restrict__ vin, const float* __restrict__ kin,
    const float* __restrict__ qin,
    const float* __restrict__ Wq, const float* __restrict__ bq,
    const float* __restrict__ Wk, const float* __restrict__ bk,
    const float* __restrict__ Wv, const float* __restrict__ bv,
    const float* __restrict__ Wo, const float* __restrict__ bo,
    float* __restrict__ out, float* __restrict__ attn)
{
    // LDS ~68.3 KB -> 2 blocks/CU.
    __shared__ ushort bufA[64*128];   // Yq bf16, 256B rows, XOR-swizzled
    __shared__ ushort bufB[64*128];   // Xk / Xv bf16, 256B rows, swizzled
    __shared__ ushort aT[64*64];      // attn bf16 [t][t2], 128B rows, swizzled
    __shared__ float  big[NT*BIGS];   // scores / V~ staging
    __shared__ float  Msh[256];       // Wq Wk^T
    __shared__ float  WvoSh[256];     // Wv Wo
    __shared__ float  bvoSh[16];      // bv Wo + bo
    __shared__ float  wkbqSh[16];     // Wk bq (score bias along t2; 0 here)
    __shared__ float  gSh[NT];
    __shared__ int    flagSh;

    const int tid  = threadIdx.x;
    const int lane = tid & 63;
    const int wv   = tid >> 6;        // 0..7
    const int b    = blockIdx.x >> 4;
    const int h    = blockIdx.x & 15;

    const float* qbase = qin + (size_t)b * NT * TOKS + h * HSL;
    const float* kbase = kin + (size_t)b * NT * TOKS + h * HSL;
    const float* vbase = vin + (size_t)b * NT * TOKS + h * HSL;

    // ---- init: zero LDS pads (rows 49..63 must be 0 for MFMA), weight products
    {
        unsigned* z0 = (unsigned*)bufA;
        unsigned* z1 = (unsigned*)bufB;
        unsigned* z2 = (unsigned*)aT;
        for (int i = tid; i < 4096; i += 512) { z0[i] = 0u; z1[i] = 0u; }
        for (int i = tid; i < 2048; i += 512) z2[i] = 0u;

        if (tid < 256) {
            int c1 = tid >> 4, c2 = tid & 15;
            float m = 0.f, wvo = 0.f;
            #pragma unroll
            for (int f = 0; f < 16; ++f) {
                m   += Wq[c1*16+f] * Wk[c2*16+f];
                wvo += Wv[c1*16+f] * Wo[f*16+c2];
            }
            Msh[tid]   = m;
            WvoSh[tid] = wvo;
        }
        if (tid < 16) {
            float s = 0.f, wb = 0.f;
            #pragma unroll
            for (int g = 0; g < 16; ++g) { s += bv[g]*Wo[g*16+tid]; wb += Wk[tid*16+g]*bq[g]; }
            bvoSh[tid]  = s + bo[tid];
            wkbqSh[tid] = wb;
        }
        if (tid < NT) gSh[tid] = 0.f;
        if (tid == 0) flagSh = 0;
    }
    __syncthreads();
    if (tid < 16 && wkbqSh[tid] != 0.f) flagSh = 1;   // benign race
    __syncthreads();
    const int hasbq = flagSh;

    // ================= phase 1: scores S[49][49], K=1024 in 8 chunks of 128
    // wave wv: M-tile (wv>>1), N-tiles {(wv&1)*2, (wv&1)*2+1}
    f32x4 accS[2];
    #pragma unroll
    for (int nt = 0; nt < 2; ++nt) accS[nt] = (f32x4){0.f,0.f,0.f,0.f};

    for (int kc = 0; kc < 8; ++kc) {
        // stage Yq = Xq*M (tasks 0..391) and Xk (tasks 392..783); 16 floats/task
        for (int idx = tid; idx < 784; idx += 512) {
            const int isK = idx >= 392;
            const int p   = isK ? idx - 392 : idx;
            const int t   = p >> 3, si = p & 7;
            const float* src = (isK ? kbase : qbase) + (size_t)t*TOKS + (kc*8 + si)*16;
            float x[16];
            *(float4*)(x)     = *(const float4*)(src);
            *(float4*)(x + 4) = *(const float4*)(src + 4);
            *(float4*)(x + 8) = *(const float4*)(src + 8);
            *(float4*)(x +12) = *(const float4*)(src +12);
            unsigned wpk[8];
            if (!isK) {
                #pragma unroll
                for (int c2 = 0; c2 < 16; c2 += 2) {
                    float y0 = 0.f, y1 = 0.f;
                    #pragma unroll
                    for (int c = 0; c < 16; ++c) {
                        y0 += x[c] * Msh[c*16 + c2];
                        y1 += x[c] * Msh[c*16 + c2 + 1];
                    }
                    wpk[c2 >> 1] = (unsigned)f2bf(y0) | ((unsigned)f2bf(y1) << 16);
                }
                const int bo_ = t*256 + si*32, sw = (t & 7) << 4;
                *(uint4*)((char*)bufA + ((bo_     ) ^ sw)) = *(uint4*)(wpk);
                *(uint4*)((char*)bufA + ((bo_ + 16) ^ sw)) = *(uint4*)(wpk + 4);
            } else {
                #pragma unroll
                for (int c = 0; c < 16; c += 2)
                    wpk[c >> 1] = (unsigned)f2bf(x[c]) | ((unsigned)f2bf(x[c+1]) << 16);
                const int bo_ = t*256 + si*32, sw = (t & 7) << 4;
                *(uint4*)((char*)bufB + ((bo_     ) ^ sw)) = *(uint4*)(wpk);
                *(uint4*)((char*)bufB + ((bo_ + 16) ^ sw)) = *(uint4*)(wpk + 4);
                if (hasbq) {
                    float pg = 0.f;
                    #pragma unroll
                    for (int c = 0; c < 16; ++c) pg += x[c] * wkbqSh[c];
                    atomicAdd(&gSh[t], pg);
                }
            }
        }
        __syncthreads();
        // K-chunk 128 = 4 ksteps
        #pragma unroll
        for (int ks = 0; ks < 4; ++ks) {
            const int ra  = (wv >> 1)*16 + (lane & 15);
            const int abo = (ra*256 + (ks*32 + (lane >> 4)*8)*2) ^ ((ra & 7) << 4);
            const bf16x8 af = *(const bf16x8*)((const char*)bufA + abo);
            #pragma unroll
            for (int nt = 0; nt < 2; ++nt) {
                const int rb  = ((wv & 1)*2 + nt)*16 + (lane & 15);
                const int bbo = (rb*256 + (ks*32 + (lane >> 4)*8)*2) ^ ((rb & 7) << 4);
                const bf16x8 bf = *(const bf16x8*)((const char*)bufB + bbo);
                accS[nt] = __builtin_amdgcn_mfma_f32_16x16x32_bf16(af, bf, accS[nt], 0, 0, 0);
            }
        }
        __syncthreads();
    }

    // write scores to big (scale 1/sqrt(1024), + g(t2) bias term)
    #pragma unroll
    for (int nt = 0; nt < 2; ++nt) {
        const int col = ((wv & 1)*2 + nt)*16 + (lane & 15);
        #pragma unroll
        for (int r = 0; r < 4; ++r) {
            const int row = (wv >> 1)*16 + (lane >> 4)*4 + r;
            if (row < NT && col < 64) {
                const float gv = (col < NT) ? gSh[col] : 0.f;
                big[row*BIGS + col] = (accS[nt][r] + gv) * 0.03125f;
            }
        }
    }
    __syncthreads();

    // softmax (one row per thread; 49 rows) -> big holds attn fp32; aT bf16
    if (tid < NT) {
        float mx = -1e30f;
        for (int j = 0; j < NT; ++j) mx = fmaxf(mx, big[tid*BIGS + j]);
        float s = 0.f;
        for (int j = 0; j < NT; ++j) {
            const float e = __expf(big[tid*BIGS + j] - mx);
            big[tid*BIGS + j] = e; s += e;
        }
        const float inv = 1.0f / s;
        for (int j = 0; j < NT; ++j) {
            const float a = big[tid*BIGS + j] * inv;
            big[tid*BIGS + j] = a;
            const int bo_ = (tid*128 + j*2) ^ ((tid & 7) << 4);
            *(ushort*)((char*)aT + bo_) = f2bf(a);
        }
    }
    __syncthreads();

    // attn output (fp32, coalesced)
    {
        float* attnb = attn + (size_t)blockIdx.x * (NT * NT);
        for (int i = tid; i < NT*NT; i += 512) {
            const int t = i / NT, j = i - t*NT;
            attnb[i] = big[t*BIGS + j];
        }
    }
    __syncthreads();

    // ================= phase 3: V~ = attn . Xv, then out = V~ Wvo + bvo
    // 8 chunks of 128 d-columns. bufB rows = 256 B (same swizzle as phase 1).
    // wave wv: M-tile (wv>>1) of tokens, N-half (wv&1) of the 128 cols.
    for (int kc = 0; kc < 8; ++kc) {
        // stage Xv chunk: 49 tokens x 8 groups of 16 floats
        for (int p = tid; p < 392; p += 512) {
            const int t = p >> 3, si = p & 7;
            const float* src = vbase + (size_t)t*TOKS + (kc*8 + si)*16;
            float x[16];
            *(float4*)(x)     = *(const float4*)(src);
            *(float4*)(x + 4) = *(const float4*)(src + 4);
            *(float4*)(x + 8) = *(const float4*)(src + 8);
            *(float4*)(x +12) = *(const float4*)(src +12);
            unsigned wpk[8];
            #pragma unroll
            for (int c = 0; c < 16; c += 2)
                wpk[c >> 1] = (unsigned)f2bf(x[c]) | ((unsigned)f2bf(x[c+1]) << 16);
            const int bo_ = t*256 + si*32, sw = (t & 7) << 4;
            *(uint4*)((char*)bufB + ((bo_     ) ^ sw)) = *(uint4*)(wpk);
            *(uint4*)((char*)bufB + ((bo_ + 16) ^ sw)) = *(uint4*)(wpk + 4);
        }
        __syncthreads();

        // MFMA: M=64 tokens, N=128 cols, K=64 t2 (2 ksteps)
        f32x4 accV[4];
        #pragma unroll
        for (int nt = 0; nt < 4; ++nt) accV[nt] = (f32x4){0.f,0.f,0.f,0.f};
        #pragma unroll
        for (int ks = 0; ks < 2; ++ks) {
            const int ra  = (wv >> 1)*16 + (lane & 15);
            const int abo = (ra*128 + (ks*32 + (lane >> 4)*8)*2) ^ ((ra & 7) << 4);
            const bf16x8 af = *(const bf16x8*)((const char*)aT + abo);
            #pragma unroll
            for (int nt = 0; nt < 4; ++nt) {
                const int n = (wv & 1)*64 + nt*16 + (lane & 15);
                bf16x8 bf;
                #pragma unroll
                for (int j = 0; j < 8; ++j) {       // u16 gather: B[k=t2][n=d]
                    const int r   = ks*32 + (lane >> 4)*8 + j;
                    const int bo_ = (r*256 + n*2) ^ ((r & 7) << 4);
                    bf[j] = *(const short*)((const char*)bufB + bo_);
                }
                accV[nt] = __builtin_amdgcn_mfma_f32_16x16x32_bf16(af, bf, accV[nt], 0, 0, 0);
            }
        }
        #pragma unroll
        for (int nt = 0; nt < 4; ++nt) {
            const int n = (wv & 1)*64 + nt*16 + (lane & 15);
            #pragma unroll
            for (int r = 0; r < 4; ++r) {
                const int row = (wv >> 1)*16 + (lane >> 4)*4 + r;
                if (row < NT) big[row*BIGS + n] = accV[nt][r];
            }
        }
        __syncthreads();

        // epilogue: out = V~ * Wvo + bvo. 16B per lane, lane-contiguous stores:
        // task p -> token t = p>>5, q = p&31 (which float4 of the 128 floats)
        for (int p = tid; p < 1568; p += 512) {
            const int t = p >> 5, q = p & 31;
            const int si = q >> 2, f2b = (q & 3) * 4;
            float o[4];
            #pragma unroll
            for (int j = 0; j < 4; ++j) {
                float s = bvoSh[f2b + j];
                #pragma unroll
                for (int f = 0; f < 16; ++f)
                    s += big[t*BIGS + si*16 + f] * WvoSh[f*16 + f2b + j];
                o[j] = s;
            }
            float* dst = out + (size_t)(b*NT + t)*TOKS + h*HSL + kc*128 + q*4;
            *(float4*)dst = *(float4*)o;
        }
        __syncthreads();
    }
}

extern "C" void kernel_launch(void* const* d_in, const int* in_sizes, int n_in,
                              void* d_out, int out_size, void* d_ws, size_t ws_size,
                              hipStream_t stream) {
    const float* v  = (const float*)d_in[0];
    const float* k  = (const float*)d_in[1];
    const float* q  = (const float*)d_in[2];
    const float* Wq = (const float*)d_in[3];
    const float* bq = (const float*)d_in[4];
    const float* Wk = (const float*)d_in[5];
    const float* bk = (const float*)d_in[6];   // softmax-row-invariant; unused
    const float* Wv = (const float*)d_in[7];
    const float* bv = (const float*)d_in[8];
    const float* Wo = (const float*)d_in[9];
    const float* bo = (const float*)d_in[10];
    (void)bk; (void)in_sizes; (void)n_in; (void)d_ws; (void)ws_size;

    float* outp  = (float*)d_out;
    float* attnp = outp + (size_t)32 * 49 * 16384;   // out | attn concat
    (void)out_size;

    lfa_fused<<<dim3(512), dim3(512), 0, stream>>>(
        v, k, q, Wq, bq, Wk, bk, Wv, bv, Wo, bo, outp, attnp);
}

// Round 3
// 368.060 us; speedup vs baseline: 2.4419x; 2.4419x over previous
//
#include <hip/hip_runtime.h>
#include <hip/hip_bf16.h>

// LFA_self: fused (proj -> MHA over 49 tokens -> proj) for MI355X.
// Algebra: scores = Xq (Wq Wk^T) Xk^T (contract over head's 1024 floats);
// out = attn . (Xv (Wv Wo)) + (bv Wo + bo)  -- per-position 16x16 projection
// commutes with the token-mixing matmul. Head h = contiguous 1024-float
// slice per token. One block per (b,h): 512 blocks, 512 threads (8 waves);
// LDS 42.3 KB + VGPR<=128 -> 2 blocks/CU (16 waves/CU).

#define NT 49            // tokens
#define TOKS 16384       // floats per (b,t)
#define HSL 1024         // floats per head slice
#define BIGS 68          // big[] row stride (floats), aliased onto bufA

typedef __attribute__((ext_vector_type(8))) short bf16x8;
typedef __attribute__((ext_vector_type(4))) float f32x4;

__device__ __forceinline__ ushort f2bf(float f) {
    union { float f; unsigned u; } v; v.f = f;
    return (ushort)((v.u + 0x7fffu + ((v.u >> 16) & 1u)) >> 16);   // RNE
}

__global__ __launch_bounds__(512, 2) void lfa_fused(
    const float* __restrict__ vin, const float* __restrict__ kin,
    const float* __restrict__ qin,
    const float* __restrict__ Wq, const float* __restrict__ bq,
    const float* __restrict__ Wk, const float* __restrict__ bk,
    const float* __restrict__ Wv, const float* __restrict__ bv,
    const float* __restrict__ Wo, const float* __restrict__ bo,
    float* __restrict__ out, float* __restrict__ attn)
{
    __shared__ ushort bufA[64*128];   // Yq bf16, 256B rows, XOR-swizzled; fp32 scores alias
    __shared__ ushort bufB[64*128];   // Xk / Z=Xv*Wvo bf16, 256B rows, swizzled
    __shared__ ushort aT[64*64];      // attn bf16 [t][t2], 128B rows, swizzled
    __shared__ float  Msh[256];       // Wq Wk^T
    __shared__ float  WvoSh[256];     // Wv Wo
    __shared__ float  bvoSh[16];      // bv Wo + bo
    __shared__ float  wkbqSh[16];     // Wk bq (score bias along t2; 0 here)
    __shared__ float  gSh[NT];
    __shared__ int    flagSh;

    float* big = (float*)bufA;        // [NT][BIGS] fp32 scores; bufA dead by then

    const int tid  = threadIdx.x;
    const int lane = tid & 63;
    const int wv   = tid >> 6;        // 0..7
    const int b    = blockIdx.x >> 4;
    const int h    = blockIdx.x & 15;

    const float* qbase = qin + (size_t)b * NT * TOKS + h * HSL;
    const float* kbase = kin + (size_t)b * NT * TOKS + h * HSL;
    const float* vbase = vin + (size_t)b * NT * TOKS + h * HSL;

    // ---- init: zero LDS pads (rows 49..63 must be 0 for MFMA), weight products
    {
        unsigned* z0 = (unsigned*)bufA;
        unsigned* z1 = (unsigned*)bufB;
        unsigned* z2 = (unsigned*)aT;
        for (int i = tid; i < 4096; i += 512) { z0[i] = 0u; z1[i] = 0u; }
        for (int i = tid; i < 2048; i += 512) z2[i] = 0u;

        if (tid < 256) {
            int c1 = tid >> 4, c2 = tid & 15;
            float m = 0.f, wvo = 0.f;
            #pragma unroll
            for (int f = 0; f < 16; ++f) {
                m   += Wq[c1*16+f] * Wk[c2*16+f];
                wvo += Wv[c1*16+f] * Wo[f*16+c2];
            }
            Msh[tid]   = m;
            WvoSh[tid] = wvo;
        }
        if (tid < 16) {
            float s = 0.f, wb = 0.f;
            #pragma unroll
            for (int g = 0; g < 16; ++g) { s += bv[g]*Wo[g*16+tid]; wb += Wk[tid*16+g]*bq[g]; }
            bvoSh[tid]  = s + bo[tid];
            wkbqSh[tid] = wb;
        }
        if (tid < NT) gSh[tid] = 0.f;
        if (tid == 0) flagSh = 0;
    }
    __syncthreads();
    if (tid < 16 && wkbqSh[tid] != 0.f) flagSh = 1;   // benign race
    __syncthreads();
    const int hasbq = flagSh;

    // ================= phase 1: scores S[49][49], K=1024 in 8 chunks of 128
    // wave wv: M-tile (wv>>1), N-tiles {(wv&1)*2, (wv&1)*2+1}
    f32x4 accS[2];
    #pragma unroll
    for (int nt = 0; nt < 2; ++nt) accS[nt] = (f32x4){0.f,0.f,0.f,0.f};

    for (int kc = 0; kc < 8; ++kc) {
        // stage Yq = Xq*M (tasks 0..391) and Xk (tasks 392..783); 16 floats/task
        for (int idx = tid; idx < 784; idx += 512) {
            const int isK = idx >= 392;
            const int p   = isK ? idx - 392 : idx;
            const int t   = p >> 3, si = p & 7;
            const float* src = (isK ? kbase : qbase) + (size_t)t*TOKS + (kc*8 + si)*16;
            float x[16];
            *(float4*)(x)     = *(const float4*)(src);
            *(float4*)(x + 4) = *(const float4*)(src + 4);
            *(float4*)(x + 8) = *(const float4*)(src + 8);
            *(float4*)(x +12) = *(const float4*)(src +12);
            unsigned wpk[8];
            if (!isK) {
                #pragma unroll
                for (int c2 = 0; c2 < 16; c2 += 2) {
                    float y0 = 0.f, y1 = 0.f;
                    #pragma unroll
                    for (int c = 0; c < 16; ++c) {
                        y0 += x[c] * Msh[c*16 + c2];
                        y1 += x[c] * Msh[c*16 + c2 + 1];
                    }
                    wpk[c2 >> 1] = (unsigned)f2bf(y0) | ((unsigned)f2bf(y1) << 16);
                }
                const int bo_ = t*256 + si*32, sw = (t & 7) << 4;
                *(uint4*)((char*)bufA + ((bo_     ) ^ sw)) = *(uint4*)(wpk);
                *(uint4*)((char*)bufA + ((bo_ + 16) ^ sw)) = *(uint4*)(wpk + 4);
            } else {
                #pragma unroll
                for (int c = 0; c < 16; c += 2)
                    wpk[c >> 1] = (unsigned)f2bf(x[c]) | ((unsigned)f2bf(x[c+1]) << 16);
                const int bo_ = t*256 + si*32, sw = (t & 7) << 4;
                *(uint4*)((char*)bufB + ((bo_     ) ^ sw)) = *(uint4*)(wpk);
                *(uint4*)((char*)bufB + ((bo_ + 16) ^ sw)) = *(uint4*)(wpk + 4);
                if (hasbq) {
                    float pg = 0.f;
                    #pragma unroll
                    for (int c = 0; c < 16; ++c) pg += x[c] * wkbqSh[c];
                    atomicAdd(&gSh[t], pg);
                }
            }
        }
        __syncthreads();
        // K-chunk 128 = 4 ksteps
        #pragma unroll
        for (int ks = 0; ks < 4; ++ks) {
            const int ra  = (wv >> 1)*16 + (lane & 15);
            const int abo = (ra*256 + (ks*32 + (lane >> 4)*8)*2) ^ ((ra & 7) << 4);
            const bf16x8 af = *(const bf16x8*)((const char*)bufA + abo);
            #pragma unroll
            for (int nt = 0; nt < 2; ++nt) {
                const int rb  = ((wv & 1)*2 + nt)*16 + (lane & 15);
                const int bbo = (rb*256 + (ks*32 + (lane >> 4)*8)*2) ^ ((rb & 7) << 4);
                const bf16x8 bf = *(const bf16x8*)((const char*)bufB + bbo);
                accS[nt] = __builtin_amdgcn_mfma_f32_16x16x32_bf16(af, bf, accS[nt], 0, 0, 0);
            }
        }
        __syncthreads();
    }

    // write scores to big (scale 1/sqrt(1024), + g(t2) bias term)
    // NOTE: big aliases bufA — all bufA reads are done (barrier above).
    #pragma unroll
    for (int nt = 0; nt < 2; ++nt) {
        const int col = ((wv & 1)*2 + nt)*16 + (lane & 15);
        #pragma unroll
        for (int r = 0; r < 4; ++r) {
            const int row = (wv >> 1)*16 + (lane >> 4)*4 + r;
            if (row < NT && col < 64) {
                const float gv = (col < NT) ? gSh[col] : 0.f;
                big[row*BIGS + col] = (accS[nt][r] + gv) * 0.03125f;
            }
        }
    }
    __syncthreads();

    // softmax (one row per thread; 49 rows) -> big holds attn fp32; aT bf16
    if (tid < NT) {
        float mx = -1e30f;
        for (int j = 0; j < NT; ++j) mx = fmaxf(mx, big[tid*BIGS + j]);
        float s = 0.f;
        for (int j = 0; j < NT; ++j) {
            const float e = __expf(big[tid*BIGS + j] - mx);
            big[tid*BIGS + j] = e; s += e;
        }
        const float inv = 1.0f / s;
        for (int j = 0; j < NT; ++j) {
            const float a = big[tid*BIGS + j] * inv;
            big[tid*BIGS + j] = a;
            const int bo_ = (tid*128 + j*2) ^ ((tid & 7) << 4);
            *(ushort*)((char*)aT + bo_) = f2bf(a);
        }
    }
    __syncthreads();

    // attn output (fp32, coalesced)
    {
        float* attnb = attn + (size_t)blockIdx.x * (NT * NT);
        for (int i = tid; i < NT*NT; i += 512) {
            const int t = i / NT, j = i - t*NT;
            attnb[i] = big[t*BIGS + j];
        }
    }
    __syncthreads();

    // ================= phase 3: out = attn . Z + bvo, Z = Xv * Wvo (bf16)
    // 8 chunks of 128 d-columns. bufB rows = 256 B (same swizzle as phase 1).
    // wave wv: M-tile (wv>>1) of tokens, N-half (wv&1) of the 128 cols.
    for (int kc = 0; kc < 8; ++kc) {
        // stage Z chunk: 49 tokens x 8 groups of 16 cols, projected by Wvo
        for (int p = tid; p < 392; p += 512) {
            const int t = p >> 3, si = p & 7;
            const float* src = vbase + (size_t)t*TOKS + (kc*8 + si)*16;
            float x[16];
            *(float4*)(x)     = *(const float4*)(src);
            *(float4*)(x + 4) = *(const float4*)(src + 4);
            *(float4*)(x + 8) = *(const float4*)(src + 8);
            *(float4*)(x +12) = *(const float4*)(src +12);
            unsigned wpk[8];
            #pragma unroll
            for (int c2 = 0; c2 < 16; c2 += 2) {
                float y0 = 0.f, y1 = 0.f;
                #pragma unroll
                for (int c = 0; c < 16; ++c) {
                    y0 += x[c] * WvoSh[c*16 + c2];
                    y1 += x[c] * WvoSh[c*16 + c2 + 1];
                }
                wpk[c2 >> 1] = (unsigned)f2bf(y0) | ((unsigned)f2bf(y1) << 16);
            }
            const int bo_ = t*256 + si*32, sw = (t & 7) << 4;
            *(uint4*)((char*)bufB + ((bo_     ) ^ sw)) = *(uint4*)(wpk);
            *(uint4*)((char*)bufB + ((bo_ + 16) ^ sw)) = *(uint4*)(wpk + 4);
        }
        __syncthreads();

        // MFMA: M=64 tokens, N=128 cols, K=64 t2 (2 ksteps); store direct
        f32x4 accV[4];
        #pragma unroll
        for (int nt = 0; nt < 4; ++nt) accV[nt] = (f32x4){0.f,0.f,0.f,0.f};
        #pragma unroll
        for (int ks = 0; ks < 2; ++ks) {
            const int ra  = (wv >> 1)*16 + (lane & 15);
            const int abo = (ra*128 + (ks*32 + (lane >> 4)*8)*2) ^ ((ra & 7) << 4);
            const bf16x8 af = *(const bf16x8*)((const char*)aT + abo);
            #pragma unroll
            for (int nt = 0; nt < 4; ++nt) {
                const int n = (wv & 1)*64 + nt*16 + (lane & 15);
                bf16x8 bf;
                #pragma unroll
                for (int j = 0; j < 8; ++j) {       // u16 gather: B[k=t2][n=d]
                    const int r   = ks*32 + (lane >> 4)*8 + j;
                    const int bo_ = (r*256 + n*2) ^ ((r & 7) << 4);
                    bf[j] = *(const short*)((const char*)bufB + bo_);
                }
                accV[nt] = __builtin_amdgcn_mfma_f32_16x16x32_bf16(af, bf, accV[nt], 0, 0, 0);
            }
        }
        // direct store from accumulator: per inst, 4 token-groups x 64B-full sectors
        #pragma unroll
        for (int nt = 0; nt < 4; ++nt) {
            const int n = (wv & 1)*64 + nt*16 + (lane & 15);
            const float bias = bvoSh[n & 15];
            #pragma unroll
            for (int r = 0; r < 4; ++r) {
                const int row = (wv >> 1)*16 + (lane >> 4)*4 + r;
                if (row < NT) {
                    out[(size_t)(b*NT + row)*TOKS + h*HSL + kc*128 + n] = accV[nt][r] + bias;
                }
            }
        }
        __syncthreads();
    }
}

extern "C" void kernel_launch(void* const* d_in, const int* in_sizes, int n_in,
                              void* d_out, int out_size, void* d_ws, size_t ws_size,
                              hipStream_t stream) {
    const float* v  = (const float*)d_in[0];
    const float* k  = (const float*)d_in[1];
    const float* q  = (const float*)d_in[2];
    const float* Wq = (const float*)d_in[3];
    const float* bq = (const float*)d_in[4];
    const float* Wk = (const float*)d_in[5];
    const float* bk = (const float*)d_in[6];   // softmax-row-invariant; unused
    const float* Wv = (const float*)d_in[7];
    const float* bv = (const float*)d_in[8];
    const float* Wo = (const float*)d_in[9];
    const float* bo = (const float*)d_in[10];
    (void)bk; (void)in_sizes; (void)n_in; (void)d_ws; (void)ws_size;

    float* outp  = (float*)d_out;
    float* attnp = outp + (size_t)32 * 49 * 16384;   // out | attn concat
    (void)out_size;

    lfa_fused<<<dim3(512), dim3(512), 0, stream>>>(
        v, k, q, Wq, bq, Wk, bk, Wv, bv, Wo, bo, outp, attnp);
}